// Round 2
// baseline (371.823 us; speedup 1.0000x reference)
//
#include <hip/hip_runtime.h>
#include <hip/hip_bf16.h>
#include <math.h>

// Problem constants
#define N_ 256
#define C_ 256
#define V_ 25
#define T_ 20
#define C4_ 64
#define O_ 256
#define VT_ 500
#define EPS_ 1e-5f

typedef unsigned short ushort_t;
typedef short short8 __attribute__((ext_vector_type(8)));
typedef float f32x4 __attribute__((ext_vector_type(4)));

__device__ __forceinline__ ushort_t f2bf(float f) {
    unsigned int u = __builtin_bit_cast(unsigned int, f);
    unsigned int r = u + 0x7fffu + ((u >> 16) & 1u);
    return (ushort_t)(r >> 16);
}

// ---------------- Kernel 1: pooled[n,c,t] = mean_v x[n,c,v,t] ----------------
__global__ __launch_bounds__(256) void k_pool(const float* __restrict__ x,
                                              float* __restrict__ pooled) {
    int idx = blockIdx.x * 256 + threadIdx.x;   // [0, N*C*T)
    int t = idx % T_;
    int nc = idx / T_;
    const float* p = x + nc * (V_ * T_) + t;
    float s = 0.f;
#pragma unroll
    for (int v = 0; v < V_; ++v) s += p[v * T_];
    pooled[idx] = s * (1.0f / V_);
}

// ---------------- Kernel 1b: Wc2 fp32 -> bf16 ----------------
__global__ __launch_bounds__(256) void k_prep(const float* __restrict__ Wc2,
                                              ushort_t* __restrict__ wbf) {
    int i = blockIdx.x * 256 + threadIdx.x;     // [0, O*C)
    wbf[i] = f2bf(Wc2[i]);
}

// ---------------- Kernel 2: G branch -> kern[n,c,3] ----------------
__global__ __launch_bounds__(256) void k_g(const float* __restrict__ Wg1,
                                           const float* __restrict__ Wg2,
                                           const float* __restrict__ bng,
                                           const float* __restrict__ pooled,
                                           float* __restrict__ kern) {
    __shared__ float wg1[800];
    __shared__ float wg2[120];
    __shared__ float sg[40], bg[40];
    int tid = threadIdx.x;
    for (int i = tid; i < 800; i += 256) wg1[i] = Wg1[i];
    if (tid < 120) wg2[tid] = Wg2[tid];
    if (tid < 40) {
        float g = bng[tid], b = bng[40 + tid];
        float m = bng[80 + tid], v = bng[120 + tid];
        float s = g * rsqrtf(v + EPS_);
        sg[tid] = s; bg[tid] = b - m * s;
    }
    __syncthreads();

    int nc = blockIdx.x * 256 + tid;
    const f32x4* pr = (const f32x4*)(pooled + nc * T_);
    float p[20];
#pragma unroll
    for (int q = 0; q < 5; ++q) {
        f32x4 v = pr[q];
        p[q*4+0] = v.x; p[q*4+1] = v.y; p[q*4+2] = v.z; p[q*4+3] = v.w;
    }
    float l0 = 0.f, l1 = 0.f, l2 = 0.f;
#pragma unroll 4
    for (int j = 0; j < 40; ++j) {
        float h = 0.f;
#pragma unroll
        for (int t = 0; t < 20; ++t) h = fmaf(wg1[j * 20 + t], p[t], h);
        h = fmaxf(fmaf(h, sg[j], bg[j]), 0.f);
        l0 = fmaf(wg2[j], h, l0);
        l1 = fmaf(wg2[40 + j], h, l1);
        l2 = fmaf(wg2[80 + j], h, l2);
    }
    float mx = fmaxf(l0, fmaxf(l1, l2));
    float e0 = __expf(l0 - mx), e1 = __expf(l1 - mx), e2 = __expf(l2 - mx);
    float inv = 1.f / (e0 + e1 + e2);
    float* kp = kern + nc * 3;
    kp[0] = e0 * inv; kp[1] = e1 * inv; kp[2] = e2 * inv;
}

// ---------------- Kernel 3: L branch -> l2out[n,c,t] (post-sigmoid) ----------------
__global__ __launch_bounds__(256) void k_l(const float* __restrict__ Wl1,
                                           const float* __restrict__ Wl2,
                                           const float* __restrict__ bnl,
                                           const float* __restrict__ pooled,
                                           float* __restrict__ l2out) {
    __shared__ float pp[C_][22];   // pooled with t zero-pad (index t+1)
    __shared__ float ls[C4_][20];
    __shared__ float sl[C4_], bl[C4_];
    int tid = threadIdx.x;
    int n = blockIdx.x;
    const float* pn = pooled + n * (C_ * T_);
    for (int i = tid; i < C_ * T_; i += 256) {
        int c = i / T_, t = i % T_;
        pp[c][t + 1] = pn[i];
    }
    pp[tid][0] = 0.f; pp[tid][21] = 0.f;
    if (tid < C4_) {
        float g = bnl[tid], b = bnl[64 + tid];
        float m = bnl[128 + tid], v = bnl[192 + tid];
        float s = g * rsqrtf(v + EPS_);
        sl[tid] = s; bl[tid] = b - m * s;
    }
    __syncthreads();
    {   // conv1: l[c4,t] over (c,k)
        int c4 = tid >> 2;
        int t0 = (tid & 3) * 5;
        float acc0 = 0.f, acc1 = 0.f, acc2 = 0.f, acc3 = 0.f, acc4 = 0.f;
        const float* w = Wl1 + c4 * (C_ * 3);
        for (int c = 0; c < C_; ++c) {
            float w0 = w[c * 3 + 0];
            float w1 = w[c * 3 + 1];
            float w2 = w[c * 3 + 2];
            float a0 = pp[c][t0 + 0], a1 = pp[c][t0 + 1], a2 = pp[c][t0 + 2];
            float a3 = pp[c][t0 + 3], a4 = pp[c][t0 + 4], a5 = pp[c][t0 + 5];
            float a6 = pp[c][t0 + 6];
            acc0 = fmaf(w0, a0, fmaf(w1, a1, fmaf(w2, a2, acc0)));
            acc1 = fmaf(w0, a1, fmaf(w1, a2, fmaf(w2, a3, acc1)));
            acc2 = fmaf(w0, a2, fmaf(w1, a3, fmaf(w2, a4, acc2)));
            acc3 = fmaf(w0, a3, fmaf(w1, a4, fmaf(w2, a5, acc3)));
            acc4 = fmaf(w0, a4, fmaf(w1, a5, fmaf(w2, a6, acc4)));
        }
        float s = sl[c4], b = bl[c4];
        ls[c4][t0 + 0] = fmaxf(fmaf(acc0, s, b), 0.f);
        ls[c4][t0 + 1] = fmaxf(fmaf(acc1, s, b), 0.f);
        ls[c4][t0 + 2] = fmaxf(fmaf(acc2, s, b), 0.f);
        ls[c4][t0 + 3] = fmaxf(fmaf(acc3, s, b), 0.f);
        ls[c4][t0 + 4] = fmaxf(fmaf(acc4, s, b), 0.f);
    }
    __syncthreads();
    {   // conv2 + sigmoid: l2[c,t] = sigma(sum_c4 Wl2[c,c4]*ls[c4,t])
        int c = tid;
        float acc[20];
#pragma unroll
        for (int t = 0; t < 20; ++t) acc[t] = 0.f;
        const float* w = Wl2 + c * C4_;
        for (int c4 = 0; c4 < C4_; ++c4) {
            float wv = w[c4];
#pragma unroll
            for (int t = 0; t < 20; ++t) acc[t] = fmaf(wv, ls[c4][t], acc[t]);
        }
        float* o = l2out + n * (C_ * T_) + c * T_;
#pragma unroll
        for (int t = 0; t < 20; ++t) o[t] = 1.f / (1.f + __expf(-acc[t]));
    }
}

// ---------------- Kernel 4: fused dynamic conv + bn1/relu + 1x1 conv (MFMA) + bn2/relu ----------------
#define YSTRIDE 264   // 256 + 8 pad shorts, keeps 16B alignment, breaks bank conflicts

__global__ __launch_bounds__(256, 2) void k_main(const float* __restrict__ x,
                                                 const ushort_t* __restrict__ wbf,
                                                 const float* __restrict__ bn1p,
                                                 const float* __restrict__ bn2p,
                                                 const float* __restrict__ kern,
                                                 const float* __restrict__ l2ws,
                                                 float* __restrict__ out) {
    __shared__ __align__(16) ushort_t yT[112 * YSTRIDE];  // [p_local][c] bf16
    __shared__ float s2t[O_], b2t[O_];
    int tid = threadIdx.x;
    int n = blockIdx.y;
    int vblk = blockIdx.x;       // 0..4, 5 v's per block

    // ---- staging: y[c, p] = relu(bn1(sum_k kern*(x^T + l2))) ----
    {
        int c = tid;
        float g1 = bn1p[c], be1 = bn1p[256 + c];
        float m1 = bn1p[512 + c], v1 = bn1p[768 + c];
        float s1 = g1 * rsqrtf(v1 + EPS_);
        float b1 = be1 - m1 * s1;
        float g2 = bn2p[c], be2 = bn2p[256 + c];
        float m2 = bn2p[512 + c], v2 = bn2p[768 + c];
        float s2 = g2 * rsqrtf(v2 + EPS_);
        s2t[c] = s2; b2t[c] = be2 - m2 * s2;

        const float* kp = kern + (n * C_ + c) * 3;
        float k0 = kp[0], k1 = kp[1], k2 = kp[2];
        float l2r[20];
        const f32x4* lp = (const f32x4*)(l2ws + (n * C_ + c) * T_);
#pragma unroll
        for (int q = 0; q < 5; ++q) {
            f32x4 v = lp[q];
            l2r[q*4+0] = v.x; l2r[q*4+1] = v.y; l2r[q*4+2] = v.z; l2r[q*4+3] = v.w;
        }
        const float* xp = x + ((n * C_ + c) * V_ + vblk * 5) * T_;
#pragma unroll
        for (int vl = 0; vl < 5; ++vl) {
            float a[22];
            a[0] = 0.f; a[21] = 0.f;
            const f32x4* xv = (const f32x4*)(xp + vl * T_);
#pragma unroll
            for (int q = 0; q < 5; ++q) {
                f32x4 u = xv[q];
                a[q*4 + 1] = u.x + l2r[q*4 + 0];
                a[q*4 + 2] = u.y + l2r[q*4 + 1];
                a[q*4 + 3] = u.z + l2r[q*4 + 2];
                a[q*4 + 4] = u.w + l2r[q*4 + 3];
            }
            ushort_t* yrow = yT + (vl * 20) * YSTRIDE + c;
#pragma unroll
            for (int t = 0; t < 20; ++t) {
                float z = fmaf(k0, a[t], fmaf(k1, a[t + 1], k2 * a[t + 2]));
                float y = fmaxf(fmaf(z, s1, b1), 0.f);
                yrow[t * YSTRIDE] = f2bf(y);
            }
        }
    }
    // zero the 12 pad rows (100..111) so MFMA reads defined data
    for (int i = tid; i < 12 * YSTRIDE; i += 256) yT[100 * YSTRIDE + i] = 0;
    __syncthreads();

    // ---- MFMA: out[o, p] = relu(bn2(sum_c Wc2[o,c]*y[c,p])) ----
    int lane = tid & 63;
    int wave = tid >> 6;
    int mrow = lane & 15;
    int kof = (lane >> 4) * 8;
    int obase = wave * 64;

    f32x4 acc[4][7];
#pragma unroll
    for (int mt = 0; mt < 4; ++mt)
#pragma unroll
        for (int ct = 0; ct < 7; ++ct) acc[mt][ct] = (f32x4){0.f, 0.f, 0.f, 0.f};

#pragma unroll 2
    for (int kk = 0; kk < C_; kk += 32) {
        short8 af[4];
        short8 bfr[7];
#pragma unroll
        for (int mt = 0; mt < 4; ++mt)
            af[mt] = *(const short8*)(wbf + (obase + mt * 16 + mrow) * C_ + kk + kof);
#pragma unroll
        for (int ct = 0; ct < 7; ++ct)
            bfr[ct] = *(const short8*)(yT + (ct * 16 + mrow) * YSTRIDE + kk + kof);
#pragma unroll
        for (int mt = 0; mt < 4; ++mt)
#pragma unroll
            for (int ct = 0; ct < 7; ++ct)
                acc[mt][ct] = __builtin_amdgcn_mfma_f32_16x16x32_bf16(af[mt], bfr[ct], acc[mt][ct], 0, 0, 0);
    }

    // ---- epilogue: bn2 + relu, store fp32 ----
    int prow = (lane >> 4) * 4;
    float* outn = out + n * (O_ * VT_);
#pragma unroll
    for (int ct = 0; ct < 7; ++ct) {
        int pl = ct * 16 + (lane & 15);
        if (pl < 100) {
            int p = vblk * 100 + pl;
#pragma unroll
            for (int mt = 0; mt < 4; ++mt) {
#pragma unroll
                for (int r = 0; r < 4; ++r) {
                    int o = obase + mt * 16 + prow + r;
                    float val = fmaxf(fmaf(acc[mt][ct][r], s2t[o], b2t[o]), 0.f);
                    outn[o * VT_ + p] = val;
                }
            }
        }
    }
}

extern "C" void kernel_launch(void* const* d_in, const int* in_sizes, int n_in,
                              void* d_out, int out_size, void* d_ws, size_t ws_size,
                              hipStream_t stream) {
    const float* x   = (const float*)d_in[0];
    const float* Wg1 = (const float*)d_in[1];
    const float* Wg2 = (const float*)d_in[2];
    const float* Wl1 = (const float*)d_in[3];
    const float* Wl2 = (const float*)d_in[4];
    const float* Wc2 = (const float*)d_in[5];
    const float* bng = (const float*)d_in[6];
    const float* bnl = (const float*)d_in[7];
    const float* bn1p = (const float*)d_in[8];
    const float* bn2p = (const float*)d_in[9];
    float* out = (float*)d_out;

    float* ws = (float*)d_ws;
    float* pooled = ws;                               // N*C*T = 1310720 floats
    float* kern   = ws + 1310720;                     // N*C*3 = 196608 floats
    float* l2ws   = ws + 1310720 + 196608;            // N*C*T = 1310720 floats
    ushort_t* wbf = (ushort_t*)(ws + 1310720 + 196608 + 1310720);  // O*C bf16

    k_pool<<<dim3((N_ * C_ * T_) / 256), dim3(256), 0, stream>>>(x, pooled);
    k_prep<<<dim3((O_ * C_) / 256), dim3(256), 0, stream>>>(Wc2, wbf);
    k_g<<<dim3(N_ * C_ / 256), dim3(256), 0, stream>>>(Wg1, Wg2, bng, pooled, kern);
    k_l<<<dim3(N_), dim3(256), 0, stream>>>(Wl1, Wl2, bnl, pooled, l2ws);
    k_main<<<dim3(5, N_), dim3(256), 0, stream>>>(x, wbf, bn1p, bn2p, kern, l2ws, out);
}